// Round 21
// baseline (657.440 us; speedup 1.0000x reference)
//
#include <hip/hip_runtime.h>
#include <hip/hip_bf16.h>

typedef unsigned short u16;
typedef __attribute__((ext_vector_type(8))) short short8;
typedef __attribute__((ext_vector_type(4))) float f32x4;

#define DIM 2048
#define HID 1408
#define NE 16
#define NTOK 2048
#define TOPK_ 4
#define SHID 2816
#define CAPROWS 10240
#define MAXTILES (CAPROWS / 128)   // 80; 80 % 8 == 0 so XCD == slot % 8
#define AUX_IDX (2048 * 2048)

__device__ inline u16 f2bf(float f) {
  __bf16 h = (__bf16)f;                 // RNE hardware convert
  return __builtin_bit_cast(u16, h);
}

__device__ inline void gload_lds16(const void* g, void* l) {
  __builtin_amdgcn_global_load_lds(
      (const __attribute__((address_space(1))) unsigned int*)g,
      (__attribute__((address_space(3))) unsigned int*)l, 16, 0, 0);
}

__device__ inline void cvt8_store(const float* __restrict__ in, u16* __restrict__ out, long i) {
  float4 a = *(const float4*)(in + i);
  float4 b = *(const float4*)(in + i + 4);
  union { u16 u[8]; uint4 v; } o;
  o.u[0] = f2bf(a.x); o.u[1] = f2bf(a.y); o.u[2] = f2bf(a.z); o.u[3] = f2bf(a.w);
  o.u[4] = f2bf(b.x); o.u[5] = f2bf(b.y); o.u[6] = f2bf(b.z); o.u[7] = f2bf(b.w);
  *(uint4*)(out + i) = o.v;
}

// ---- gate f64 logits (blocks 0..2047)  ||  cvt x->bf16 (128 tail blocks) ----
__global__ __launch_bounds__(256) void gatecvt_kernel(
    const float* __restrict__ x, const float* __restrict__ gw,
    double* __restrict__ logits, u16* __restrict__ xb) {
  if ((int)blockIdx.x >= NTOK) {
    long i0 = ((long)(blockIdx.x - NTOK) * 256 + threadIdx.x) * 8;
    long stride = (long)(gridDim.x - NTOK) * 2048;
    for (long i = i0; i < (long)NTOK * DIM; i += stride) cvt8_store(x, xb, i);
    return;
  }
  int t = blockIdx.x;
  const float* xt = x + (size_t)t * DIM;
  __shared__ double red[NE][4];
  int lane = threadIdx.x & 63, wid = threadIdx.x >> 6;
  for (int e = 0; e < NE; ++e) {
    const float* w = gw + e * DIM;
    double p = 0.0;
    for (int d = threadIdx.x; d < DIM; d += 256)
      p += (double)xt[d] * (double)w[d];
#pragma unroll
    for (int s = 32; s; s >>= 1) p += __shfl_xor(p, s);
    if (lane == 0) red[e][wid] = p;
  }
  __syncthreads();
  if (threadIdx.x < NE)
    logits[(size_t)t * NE + threadIdx.x] =
        red[threadIdx.x][0] + red[threadIdx.x][1] + red[threadIdx.x][2] + red[threadIdx.x][3];
}

// ---------------- gate phase 2: per-token softmax + top-4 ----------------
__global__ __launch_bounds__(256) void topk_kernel(
    const double* __restrict__ logits,
    int* __restrict__ idxb, float* __restrict__ wtb,
    int* __restrict__ counts, float* __restrict__ ssum) {
  __shared__ int lcnt[NE];
  __shared__ float lsum[NE];
  if (threadIdx.x < NE) { lcnt[threadIdx.x] = 0; lsum[threadIdx.x] = 0.f; }
  __syncthreads();
  int t = blockIdx.x * 256 + threadIdx.x;
  int lane = threadIdx.x & 63;
  double sc[NE];
  double m = -1e300;
#pragma unroll
  for (int e = 0; e < NE; ++e) {
    sc[e] = logits[(size_t)t * NE + e];
    if (sc[e] > m) m = sc[e];
  }
  double s = 0.0;
#pragma unroll
  for (int e = 0; e < NE; ++e) { sc[e] = exp(sc[e] - m); s += sc[e]; }
  double inv = 1.0 / s;
#pragma unroll
  for (int e = 0; e < NE; ++e) sc[e] *= inv;
  unsigned used = 0;
  for (int k = 0; k < TOPK_; ++k) {
    int be = 0; double bv = -1.0;
#pragma unroll
    for (int e = 0; e < NE; ++e)
      if (!((used >> e) & 1u) && sc[e] > bv) { bv = sc[e]; be = e; }
    used |= 1u << be;
    idxb[t * TOPK_ + k] = be;
    wtb[t * TOPK_ + k] = (float)bv;     // ROUTE_SCALE = 1
    atomicAdd(&lcnt[be], 1);
  }
#pragma unroll
  for (int e = 0; e < NE; ++e) {
    float v = (float)sc[e];
#pragma unroll
    for (int sft = 32; sft; sft >>= 1) v += __shfl_xor(v, sft);
    if (lane == 0) atomicAdd(&lsum[e], v);
  }
  __syncthreads();
  if (threadIdx.x < NE) {
    atomicAdd(&counts[threadIdx.x], lcnt[threadIdx.x]);
    atomicAdd(&ssum[threadIdx.x], lsum[threadIdx.x]);
  }
}

// -------- segment offsets (128-padded), XCD-grouped tile map, aux loss --------
__global__ __launch_bounds__(256) void setup_kernel(
    const int* __restrict__ counts, int* __restrict__ off, int* __restrict__ cap,
    const float* __restrict__ ssum, int* __restrict__ perm, float* __restrict__ pwt,
    float* __restrict__ aux_out,
    int* __restrict__ tile2e, int* __restrict__ tile2m0) {
  for (int i = threadIdx.x; i < MAXTILES; i += 256) tile2e[i] = -1;
  __syncthreads();
  if (threadIdx.x == 0) {
    int o = 0; double aux = 0.0; int nt = 0;
    for (int e = 0; e < NE; ++e) {
      off[e] = o;
      int c = (counts[e] + 127) & ~127;
      cap[e] = c;
      for (int t = 0; t < (c >> 7); ++t) {
        int slot = (nt / 10) + (nt % 10) * 8;
        tile2e[slot] = e;
        tile2m0[slot] = o + t * 128;
        ++nt;
      }
      o += c;
      aux += ((double)counts[e] / (NTOK * TOPK_)) * ((double)ssum[e] / NTOK);
    }
    aux_out[0] = (float)(NE * aux);
  }
  for (int i = threadIdx.x; i < CAPROWS; i += 256) { perm[i] = 0; pwt[i] = 0.f; }
}

__global__ __launch_bounds__(256) void scatter_kernel(
    const int* __restrict__ idxb, const float* __restrict__ wtb,
    const int* __restrict__ off, int* __restrict__ cursor,
    int* __restrict__ perm, float* __restrict__ pwt) {
  int t = blockIdx.x * 256 + threadIdx.x;
  if (t >= NTOK) return;
  for (int k = 0; k < TOPK_; ++k) {
    int e = idxb[t * TOPK_ + k];
    int s = atomicAdd(&cursor[e], 1);
    int p = off[e] + s;
    perm[p] = t;
    pwt[p] = wtb[t * TOPK_ + k];
  }
}

// ====== GEMM v12s: R16 verified schedule + T5 setprio around MFMA clusters ======
// Mechanism: 2-3 blocks/CU sit at DIFFERENT K-phases; setprio(1) on the MFMA
// cluster biases SIMD arbitration toward compute-phase waves while other blocks
// issue staging (m114 overlap). Waves within a block are lockstep (m190 null
// case), so expected delta is small; zero correctness risk.
template <bool GATHER, bool DUAL, int EPI>
__global__ __launch_bounds__(512) void gemm12_kernel(
    const u16* __restrict__ A, int lda,
    const float* __restrict__ B1, const float* __restrict__ B3,
    int ldb, long bstride, int K,
    const int* __restrict__ tile2e, const int* __restrict__ tile2m0,
    const int* __restrict__ seg_off, const int* __restrict__ seg_cnt,
    const int* __restrict__ perm, const float* __restrict__ pwt,
    float* __restrict__ C0, int ldc0,
    u16* __restrict__ Cb, int ldcb, int Mfixed) {
  int e, m0, rowlim;
  if (tile2e) {
    e = tile2e[blockIdx.x];
    if (e < 0) return;
    m0 = tile2m0[blockIdx.x];
    rowlim = seg_off[e] + seg_cnt[e];
  } else {
    e = 0;
    m0 = blockIdx.x * 128;
    if (m0 >= Mfixed) return;
    rowlim = Mfixed;
  }
  int n0 = blockIdx.y * 64;
  const float* Bb1 = B1 + (long)e * bstride;
  const float* Bb3 = DUAL ? (B3 + (long)e * bstride) : nullptr;

  __shared__ u16 As[2][128 * 64];               // 2 x 16 KB (A dbuf: async 1-ahead)
  __shared__ u16 Bs1[64 * 64];                  // 8 KB single (written post-barrier)
  __shared__ u16 Bs3[DUAL ? 64 * 64 : 1];

  int tid = threadIdx.x;
  int lane = tid & 63;
  int wid = tid >> 6;                 // 0..7
  int wr = wid >> 1, wc = wid & 1;    // 4 m-quarters x 2 n-halves

  f32x4 acc1[2][2], acc3[2][2];
#pragma unroll
  for (int mi = 0; mi < 2; ++mi)
#pragma unroll
    for (int ni = 0; ni < 2; ++ni) {
      acc1[mi][ni] = (f32x4){0.f, 0.f, 0.f, 0.f};
      acc3[mi][ni] = (f32x4){0.f, 0.f, 0.f, 0.f};
    }

  // ---- A staging: row = it*64 + (tid>>3), chunk = tid&7; SOURCE chunk XOR'd ----
  int sr = tid >> 3;                  // 0..63
  int scA = tid & 7;
  long abase[2];
#pragma unroll
  for (int it = 0; it < 2; ++it) {
    int row = m0 + it * 64 + sr;
    int rid = GATHER ? perm[row] : row;
    abase[it] = (long)rid * lda + ((scA ^ (sr & 7)) << 3);
  }
  // ---- B staging: row = it*32 + (tid>>4), 8B granule g=tid&15; swizzle at LDS WRITE ----
  int brr = tid >> 4;                 // 0..31
  int gB = tid & 15;
  int wofs = (((gB >> 1) ^ (brr & 7)) << 3) + ((gB & 1) << 2);   // u16 units in row
  long bbase[2];
#pragma unroll
  for (int it = 0; it < 2; ++it)
    bbase[it] = (long)(n0 + it * 32 + brr) * ldb + gB * 4;       // linear f32 source

  float4 R1a[2], R3a[2], R1b[2], R3b[2];       // two static reg buffers (depth-2)

  auto stageA = [&](int buf, int k0) {
#pragma unroll
    for (int it = 0; it < 2; ++it)
      gload_lds16(A + abase[it] + k0, &As[buf][(it * 64 + sr) * 64 + scA * 8]);
  };
  auto loadB = [&](float4 (&r1)[2], float4 (&r3)[2], int k0) {
#pragma unroll
    for (int it = 0; it < 2; ++it) r1[it] = *(const float4*)(Bb1 + bbase[it] + k0);
    if (DUAL) {
#pragma unroll
      for (int it = 0; it < 2; ++it) r3[it] = *(const float4*)(Bb3 + bbase[it] + k0);
    }
  };
  auto writeB = [&](float4 (&r1)[2], float4 (&r3)[2]) {
#pragma unroll
    for (int it = 0; it < 2; ++it) {
      int lo = (it * 32 + brr) * 64 + wofs;
      ushort4 o;
      o.x = f2bf(r1[it].x); o.y = f2bf(r1[it].y); o.z = f2bf(r1[it].z); o.w = f2bf(r1[it].w);
      *(ushort4*)&Bs1[lo] = o;
      if (DUAL) {
        ushort4 q;
        q.x = f2bf(r3[it].x); q.y = f2bf(r3[it].y); q.z = f2bf(r3[it].z); q.w = f2bf(r3[it].w);
        *(ushort4*)&Bs3[lo] = q;
      }
    }
  };
  auto compute = [&](int cur) {
#pragma unroll
    for (int kk = 0; kk < 64; kk += 32) {
      short8 af[2], b1f[2], b3f[2];
#pragma unroll
      for (int i = 0; i < 2; ++i) {
        int R = wr * 32 + i * 16 + (lane & 15);
        int c = (kk >> 3) + (lane >> 4);
        af[i] = *(const short8*)&As[cur][R * 64 + ((c ^ (R & 7)) << 3)];
      }
#pragma unroll
      for (int i = 0; i < 2; ++i) {
        int r = wc * 32 + i * 16 + (lane & 15);
        int cR = (kk >> 3) + (lane >> 4);
        b1f[i] = *(const short8*)&Bs1[r * 64 + ((cR ^ (r & 7)) << 3)];
        if (DUAL)
          b3f[i] = *(const short8*)&Bs3[r * 64 + ((cR ^ (r & 7)) << 3)];
      }
      __builtin_amdgcn_s_setprio(1);          // T5: favor MFMA-phase waves
#pragma unroll
      for (int mi = 0; mi < 2; ++mi)
#pragma unroll
        for (int ni = 0; ni < 2; ++ni) {
          acc1[mi][ni] = __builtin_amdgcn_mfma_f32_16x16x32_bf16(af[mi], b1f[ni], acc1[mi][ni], 0, 0, 0);
          if (DUAL)
            acc3[mi][ni] = __builtin_amdgcn_mfma_f32_16x16x32_bf16(af[mi], b3f[ni], acc3[mi][ni], 0, 0, 0);
        }
      __builtin_amdgcn_s_setprio(0);
    }
  };

  int NT = K >> 6;                   // 22 / 32 / 44 — always even, >= 4
  loadB(R1a, R3a, 0);
  stageA(0, 0);
  loadB(R1b, R3b, 64);

#define GEMM12_STEP(T, CUR, RB1, RB3)                                         \
  {                                                                           \
    int t_ = (T);                                                             \
    writeB(RB1, RB3);                      /* drains B(t): 2 iters old */     \
    bool hasA = (t_ + 1 < NT), hasB = (t_ + 2 < NT);                          \
    if (hasA) stageA((CUR) ^ 1, (t_ + 1) << 6);                               \
    if (hasB) loadB(RB1, RB3, (t_ + 2) << 6);                                 \
    if (hasB) {                                                               \
      if (DUAL) asm volatile("s_waitcnt vmcnt(10)" ::: "memory");             \
      else      asm volatile("s_waitcnt vmcnt(6)" ::: "memory");              \
    } else if (hasA) {                                                        \
      if (DUAL) asm volatile("s_waitcnt vmcnt(6)" ::: "memory");              \
      else      asm volatile("s_waitcnt vmcnt(4)" ::: "memory");              \
    } else {                                                                  \
      asm volatile("s_waitcnt vmcnt(0)" ::: "memory");                        \
    }                                                                         \
    asm volatile("s_waitcnt lgkmcnt(0)" ::: "memory");                        \
    __builtin_amdgcn_sched_barrier(0);                                        \
    __builtin_amdgcn_s_barrier();          /* tile t fully in LDS */          \
    __builtin_amdgcn_sched_barrier(0);                                        \
    compute(CUR);                                                             \
    __builtin_amdgcn_sched_barrier(0);                                        \
    __builtin_amdgcn_s_barrier();          /* all reads of Bs/As[cur] done */ \
  }

  for (int t = 0; t < NT; t += 2) {
    GEMM12_STEP(t,     0, R1a, R3a);
    GEMM12_STEP(t + 1, 1, R1b, R3b);
  }
#undef GEMM12_STEP

  int rbase = m0 + wr * 32 + (lane >> 4) * 4;
  int cbase = n0 + wc * 32 + (lane & 15);
#pragma unroll
  for (int mi = 0; mi < 2; ++mi) {
#pragma unroll
    for (int ni = 0; ni < 2; ++ni) {
      int col = cbase + ni * 16;
#pragma unroll
      for (int r = 0; r < 4; ++r) {
        int row = rbase + mi * 16 + r;
        float v = acc1[mi][ni][r];
        if (EPI == 0) {
          float a3 = acc3[mi][ni][r];
          float sg = v / (1.f + __expf(-v));
          Cb[(long)row * ldcb + col] = f2bf(sg * a3);
        } else if (EPI == 1) {
          C0[(long)row * ldc0 + col] = v;
        } else {
          if (row < rowlim) {
            atomicAdd(&C0[(long)perm[row] * ldc0 + col], v * pwt[row]);
          }
        }
      }
    }
  }
}

extern "C" void kernel_launch(void* const* d_in, const int* in_sizes, int n_in,
                              void* d_out, int out_size, void* d_ws, size_t ws_size,
                              hipStream_t stream) {
  (void)in_sizes; (void)n_in; (void)out_size; (void)ws_size;
  const float* x   = (const float*)d_in[0];
  const float* gw  = (const float*)d_in[1];
  const float* w1  = (const float*)d_in[2];
  const float* w2  = (const float*)d_in[3];
  const float* w3  = (const float*)d_in[4];
  const float* sw1 = (const float*)d_in[5];
  const float* sw2 = (const float*)d_in[6];
  const float* sw3 = (const float*)d_in[7];
  float* out = (float*)d_out;
  char* ws = (char*)d_ws;

  int*   counts = (int*)(ws + 0);
  int*   cursor = (int*)(ws + 64);
  int*   off    = (int*)(ws + 128);
  int*   cap    = (int*)(ws + 192);
  float* ssum   = (float*)(ws + 256);
  int*   tile2e = (int*)(ws + 1024);
  int*   tile2m0= (int*)(ws + 2048);
  int*   idxb   = (int*)(ws + 4096);
  float* wtb    = (float*)(ws + 4096 + 32768);
  int*   perm   = (int*)(ws + 4096 + 65536);
  float* pwt    = (float*)(ws + 4096 + 65536 + 40960);
  u16*   xb     = (u16*)(ws + 262144);                 // 2048x2048 bf16
  double* logits = (double*)(ws + 8650752);            // 2048x16 f64
  u16*   hbuf   = (u16*)(ws + 16777216);               // 10240x1408 bf16
  u16*   hsb    = (u16*)(ws + 45613056);               // 2048x2816 bf16

  hipMemsetAsync(ws, 0, 512, stream);
  gatecvt_kernel<<<dim3(NTOK + 128), dim3(256), 0, stream>>>(x, gw, logits, xb);
  topk_kernel<<<dim3(NTOK / 256), dim3(256), 0, stream>>>(logits, idxb, wtb, counts, ssum);
  setup_kernel<<<dim3(1), dim3(256), 0, stream>>>(counts, off, cap, ssum, perm, pwt,
                                                  out + AUX_IDX, tile2e, tile2m0);
  scatter_kernel<<<dim3(8), dim3(256), 0, stream>>>(idxb, wtb, off, cursor, perm, pwt);

  // routed h = silu(gather(x)@w1^T) * (gather(x)@w3^T) -> bf16
  gemm12_kernel<true, true, 0><<<dim3(MAXTILES, HID / 64), dim3(512), 0, stream>>>(
      xb, DIM, w1, w3, DIM, (long)HID * DIM, DIM, tile2e, tile2m0,
      off, counts, perm, pwt, nullptr, 0, hbuf, HID, 0);
  // shared hs = silu(x@sw1^T) * (x@sw3^T) -> bf16
  gemm12_kernel<false, true, 0><<<dim3(NTOK / 128, SHID / 64), dim3(512), 0, stream>>>(
      xb, DIM, sw1, sw3, DIM, 0, DIM, nullptr, nullptr,
      nullptr, nullptr, nullptr, nullptr, nullptr, 0, hsb, SHID, NTOK);
  // z = hs @ sw2^T  (plain f32 store into out)
  gemm12_kernel<false, false, 1><<<dim3(NTOK / 128, DIM / 64), dim3(512), 0, stream>>>(
      hsb, SHID, sw2, nullptr, SHID, 0, SHID, nullptr, nullptr,
      nullptr, nullptr, nullptr, nullptr, out, DIM, nullptr, 0, NTOK);
  // out += (h @ w2^T) * pwt   (atomic accumulate on top of z)
  gemm12_kernel<false, false, 2><<<dim3(MAXTILES, DIM / 64), dim3(512), 0, stream>>>(
      hbuf, HID, w2, nullptr, HID, (long)DIM * HID, HID, tile2e, tile2m0,
      off, counts, perm, pwt, out, DIM, nullptr, 0, 0);
}

// Round 22
// 576.443 us; speedup vs baseline: 1.1405x; 1.1405x over previous
//
#include <hip/hip_runtime.h>
#include <hip/hip_bf16.h>

typedef unsigned short u16;
typedef __attribute__((ext_vector_type(8))) short short8;
typedef __attribute__((ext_vector_type(4))) float f32x4;

#define DIM 2048
#define HID 1408
#define NE 16
#define NTOK 2048
#define TOPK_ 4
#define SHID 2816
#define CAPROWS 10240
#define MAXTILES (CAPROWS / 128)   // 80; 80 % 8 == 0 so XCD == slot % 8
#define AUX_IDX (2048 * 2048)

__device__ inline u16 f2bf(float f) {
  __bf16 h = (__bf16)f;                 // RNE hardware convert
  return __builtin_bit_cast(u16, h);
}

__device__ inline void gload_lds16(const void* g, void* l) {
  __builtin_amdgcn_global_load_lds(
      (const __attribute__((address_space(1))) unsigned int*)g,
      (__attribute__((address_space(3))) unsigned int*)l, 16, 0, 0);
}

__device__ inline void cvt8_store(const float* __restrict__ in, u16* __restrict__ out, long i) {
  float4 a = *(const float4*)(in + i);
  float4 b = *(const float4*)(in + i + 4);
  union { u16 u[8]; uint4 v; } o;
  o.u[0] = f2bf(a.x); o.u[1] = f2bf(a.y); o.u[2] = f2bf(a.z); o.u[3] = f2bf(a.w);
  o.u[4] = f2bf(b.x); o.u[5] = f2bf(b.y); o.u[6] = f2bf(b.z); o.u[7] = f2bf(b.w);
  *(uint4*)(out + i) = o.v;
}

// ---- gate f64 logits (blocks 0..2047)  ||  cvt x->bf16 (128 tail blocks) ----
__global__ __launch_bounds__(256) void gatecvt_kernel(
    const float* __restrict__ x, const float* __restrict__ gw,
    double* __restrict__ logits, u16* __restrict__ xb) {
  if ((int)blockIdx.x >= NTOK) {
    long i0 = ((long)(blockIdx.x - NTOK) * 256 + threadIdx.x) * 8;
    long stride = (long)(gridDim.x - NTOK) * 2048;
    for (long i = i0; i < (long)NTOK * DIM; i += stride) cvt8_store(x, xb, i);
    return;
  }
  int t = blockIdx.x;
  const float* xt = x + (size_t)t * DIM;
  __shared__ double red[NE][4];
  int lane = threadIdx.x & 63, wid = threadIdx.x >> 6;
  for (int e = 0; e < NE; ++e) {
    const float* w = gw + e * DIM;
    double p = 0.0;
    for (int d = threadIdx.x; d < DIM; d += 256)
      p += (double)xt[d] * (double)w[d];
#pragma unroll
    for (int s = 32; s; s >>= 1) p += __shfl_xor(p, s);
    if (lane == 0) red[e][wid] = p;
  }
  __syncthreads();
  if (threadIdx.x < NE)
    logits[(size_t)t * NE + threadIdx.x] =
        red[threadIdx.x][0] + red[threadIdx.x][1] + red[threadIdx.x][2] + red[threadIdx.x][3];
}

// ---------------- gate phase 2: per-token softmax + top-4 ----------------
__global__ __launch_bounds__(256) void topk_kernel(
    const double* __restrict__ logits,
    int* __restrict__ idxb, float* __restrict__ wtb,
    int* __restrict__ counts, float* __restrict__ ssum) {
  __shared__ int lcnt[NE];
  __shared__ float lsum[NE];
  if (threadIdx.x < NE) { lcnt[threadIdx.x] = 0; lsum[threadIdx.x] = 0.f; }
  __syncthreads();
  int t = blockIdx.x * 256 + threadIdx.x;
  int lane = threadIdx.x & 63;
  double sc[NE];
  double m = -1e300;
#pragma unroll
  for (int e = 0; e < NE; ++e) {
    sc[e] = logits[(size_t)t * NE + e];
    if (sc[e] > m) m = sc[e];
  }
  double s = 0.0;
#pragma unroll
  for (int e = 0; e < NE; ++e) { sc[e] = exp(sc[e] - m); s += sc[e]; }
  double inv = 1.0 / s;
#pragma unroll
  for (int e = 0; e < NE; ++e) sc[e] *= inv;
  unsigned used = 0;
  for (int k = 0; k < TOPK_; ++k) {
    int be = 0; double bv = -1.0;
#pragma unroll
    for (int e = 0; e < NE; ++e)
      if (!((used >> e) & 1u) && sc[e] > bv) { bv = sc[e]; be = e; }
    used |= 1u << be;
    idxb[t * TOPK_ + k] = be;
    wtb[t * TOPK_ + k] = (float)bv;     // ROUTE_SCALE = 1
    atomicAdd(&lcnt[be], 1);
  }
#pragma unroll
  for (int e = 0; e < NE; ++e) {
    float v = (float)sc[e];
#pragma unroll
    for (int sft = 32; sft; sft >>= 1) v += __shfl_xor(v, sft);
    if (lane == 0) atomicAdd(&lsum[e], v);
  }
  __syncthreads();
  if (threadIdx.x < NE) {
    atomicAdd(&counts[threadIdx.x], lcnt[threadIdx.x]);
    atomicAdd(&ssum[threadIdx.x], lsum[threadIdx.x]);
  }
}

// -------- segment offsets (128-padded), XCD-grouped tile map, aux loss --------
__global__ __launch_bounds__(256) void setup_kernel(
    const int* __restrict__ counts, int* __restrict__ off, int* __restrict__ cap,
    const float* __restrict__ ssum, int* __restrict__ perm, float* __restrict__ pwt,
    float* __restrict__ aux_out,
    int* __restrict__ tile2e, int* __restrict__ tile2m0) {
  for (int i = threadIdx.x; i < MAXTILES; i += 256) tile2e[i] = -1;
  __syncthreads();
  if (threadIdx.x == 0) {
    int o = 0; double aux = 0.0; int nt = 0;
    for (int e = 0; e < NE; ++e) {
      off[e] = o;
      int c = (counts[e] + 127) & ~127;
      cap[e] = c;
      for (int t = 0; t < (c >> 7); ++t) {
        int slot = (nt / 10) + (nt % 10) * 8;
        tile2e[slot] = e;
        tile2m0[slot] = o + t * 128;
        ++nt;
      }
      o += c;
      aux += ((double)counts[e] / (NTOK * TOPK_)) * ((double)ssum[e] / NTOK);
    }
    aux_out[0] = (float)(NE * aux);
  }
  for (int i = threadIdx.x; i < CAPROWS; i += 256) { perm[i] = 0; pwt[i] = 0.f; }
}

__global__ __launch_bounds__(256) void scatter_kernel(
    const int* __restrict__ idxb, const float* __restrict__ wtb,
    const int* __restrict__ off, int* __restrict__ cursor,
    int* __restrict__ perm, float* __restrict__ pwt) {
  int t = blockIdx.x * 256 + threadIdx.x;
  if (t >= NTOK) return;
  for (int k = 0; k < TOPK_; ++k) {
    int e = idxb[t * TOPK_ + k];
    int s = atomicAdd(&cursor[e], 1);
    int p = off[e] + s;
    perm[p] = t;
    pwt[p] = wtb[t * TOPK_ + k];
  }
}

// ====== GEMM v12 (best verified, R16/R19: 576.7/578.3 us): 512T/8 waves, 128x64 tile ======
// A: bf16 gload_lds dbuf 2x16KB, source pre-swizzled chunk^=(row&7); 2 gloads/thread.
// B: f32 -> regs depth-2 (2 float4/matrix/thread) -> cvt -> bf16 LDS single (swizzled).
// Per-wave vmcnt (per step issue: A=2, B=4 dual / 2 single):
//   dual steady vmcnt(10), tail 6, last 0; single steady 6, tail 4, last 0.
// NOTE: no setprio — measured -80 us (R20); no BM=256 — measured -70 us (R18);
// no 1024T — measured -80 us (R17). This point is the measured optimum.
template <bool GATHER, bool DUAL, int EPI>
__global__ __launch_bounds__(512) void gemm12_kernel(
    const u16* __restrict__ A, int lda,
    const float* __restrict__ B1, const float* __restrict__ B3,
    int ldb, long bstride, int K,
    const int* __restrict__ tile2e, const int* __restrict__ tile2m0,
    const int* __restrict__ seg_off, const int* __restrict__ seg_cnt,
    const int* __restrict__ perm, const float* __restrict__ pwt,
    float* __restrict__ C0, int ldc0,
    u16* __restrict__ Cb, int ldcb, int Mfixed) {
  int e, m0, rowlim;
  if (tile2e) {
    e = tile2e[blockIdx.x];
    if (e < 0) return;
    m0 = tile2m0[blockIdx.x];
    rowlim = seg_off[e] + seg_cnt[e];
  } else {
    e = 0;
    m0 = blockIdx.x * 128;
    if (m0 >= Mfixed) return;
    rowlim = Mfixed;
  }
  int n0 = blockIdx.y * 64;
  const float* Bb1 = B1 + (long)e * bstride;
  const float* Bb3 = DUAL ? (B3 + (long)e * bstride) : nullptr;

  __shared__ u16 As[2][128 * 64];               // 2 x 16 KB (A dbuf: async 1-ahead)
  __shared__ u16 Bs1[64 * 64];                  // 8 KB single (written post-barrier)
  __shared__ u16 Bs3[DUAL ? 64 * 64 : 1];

  int tid = threadIdx.x;
  int lane = tid & 63;
  int wid = tid >> 6;                 // 0..7
  int wr = wid >> 1, wc = wid & 1;    // 4 m-quarters x 2 n-halves

  f32x4 acc1[2][2], acc3[2][2];
#pragma unroll
  for (int mi = 0; mi < 2; ++mi)
#pragma unroll
    for (int ni = 0; ni < 2; ++ni) {
      acc1[mi][ni] = (f32x4){0.f, 0.f, 0.f, 0.f};
      acc3[mi][ni] = (f32x4){0.f, 0.f, 0.f, 0.f};
    }

  // ---- A staging: row = it*64 + (tid>>3), chunk = tid&7; SOURCE chunk XOR'd ----
  int sr = tid >> 3;                  // 0..63
  int scA = tid & 7;
  long abase[2];
#pragma unroll
  for (int it = 0; it < 2; ++it) {
    int row = m0 + it * 64 + sr;
    int rid = GATHER ? perm[row] : row;
    abase[it] = (long)rid * lda + ((scA ^ (sr & 7)) << 3);
  }
  // ---- B staging: row = it*32 + (tid>>4), 8B granule g=tid&15; swizzle at LDS WRITE ----
  int brr = tid >> 4;                 // 0..31
  int gB = tid & 15;
  int wofs = (((gB >> 1) ^ (brr & 7)) << 3) + ((gB & 1) << 2);   // u16 units in row
  long bbase[2];
#pragma unroll
  for (int it = 0; it < 2; ++it)
    bbase[it] = (long)(n0 + it * 32 + brr) * ldb + gB * 4;       // linear f32 source

  float4 R1a[2], R3a[2], R1b[2], R3b[2];       // two static reg buffers (depth-2)

  auto stageA = [&](int buf, int k0) {
#pragma unroll
    for (int it = 0; it < 2; ++it)
      gload_lds16(A + abase[it] + k0, &As[buf][(it * 64 + sr) * 64 + scA * 8]);
  };
  auto loadB = [&](float4 (&r1)[2], float4 (&r3)[2], int k0) {
#pragma unroll
    for (int it = 0; it < 2; ++it) r1[it] = *(const float4*)(Bb1 + bbase[it] + k0);
    if (DUAL) {
#pragma unroll
      for (int it = 0; it < 2; ++it) r3[it] = *(const float4*)(Bb3 + bbase[it] + k0);
    }
  };
  auto writeB = [&](float4 (&r1)[2], float4 (&r3)[2]) {
#pragma unroll
    for (int it = 0; it < 2; ++it) {
      int lo = (it * 32 + brr) * 64 + wofs;
      ushort4 o;
      o.x = f2bf(r1[it].x); o.y = f2bf(r1[it].y); o.z = f2bf(r1[it].z); o.w = f2bf(r1[it].w);
      *(ushort4*)&Bs1[lo] = o;
      if (DUAL) {
        ushort4 q;
        q.x = f2bf(r3[it].x); q.y = f2bf(r3[it].y); q.z = f2bf(r3[it].z); q.w = f2bf(r3[it].w);
        *(ushort4*)&Bs3[lo] = q;
      }
    }
  };
  auto compute = [&](int cur) {
#pragma unroll
    for (int kk = 0; kk < 64; kk += 32) {
      short8 af[2], b1f[2], b3f[2];
#pragma unroll
      for (int i = 0; i < 2; ++i) {
        int R = wr * 32 + i * 16 + (lane & 15);
        int c = (kk >> 3) + (lane >> 4);
        af[i] = *(const short8*)&As[cur][R * 64 + ((c ^ (R & 7)) << 3)];
      }
#pragma unroll
      for (int i = 0; i < 2; ++i) {
        int r = wc * 32 + i * 16 + (lane & 15);
        int cR = (kk >> 3) + (lane >> 4);
        b1f[i] = *(const short8*)&Bs1[r * 64 + ((cR ^ (r & 7)) << 3)];
        if (DUAL)
          b3f[i] = *(const short8*)&Bs3[r * 64 + ((cR ^ (r & 7)) << 3)];
      }
#pragma unroll
      for (int mi = 0; mi < 2; ++mi)
#pragma unroll
        for (int ni = 0; ni < 2; ++ni) {
          acc1[mi][ni] = __builtin_amdgcn_mfma_f32_16x16x32_bf16(af[mi], b1f[ni], acc1[mi][ni], 0, 0, 0);
          if (DUAL)
            acc3[mi][ni] = __builtin_amdgcn_mfma_f32_16x16x32_bf16(af[mi], b3f[ni], acc3[mi][ni], 0, 0, 0);
        }
    }
  };

  int NT = K >> 6;                   // 22 / 32 / 44 — always even, >= 4
  loadB(R1a, R3a, 0);
  stageA(0, 0);
  loadB(R1b, R3b, 64);

#define GEMM12_STEP(T, CUR, RB1, RB3)                                         \
  {                                                                           \
    int t_ = (T);                                                             \
    writeB(RB1, RB3);                      /* drains B(t): 2 iters old */     \
    bool hasA = (t_ + 1 < NT), hasB = (t_ + 2 < NT);                          \
    if (hasA) stageA((CUR) ^ 1, (t_ + 1) << 6);                               \
    if (hasB) loadB(RB1, RB3, (t_ + 2) << 6);                                 \
    if (hasB) {                                                               \
      if (DUAL) asm volatile("s_waitcnt vmcnt(10)" ::: "memory");             \
      else      asm volatile("s_waitcnt vmcnt(6)" ::: "memory");              \
    } else if (hasA) {                                                        \
      if (DUAL) asm volatile("s_waitcnt vmcnt(6)" ::: "memory");              \
      else      asm volatile("s_waitcnt vmcnt(4)" ::: "memory");              \
    } else {                                                                  \
      asm volatile("s_waitcnt vmcnt(0)" ::: "memory");                        \
    }                                                                         \
    asm volatile("s_waitcnt lgkmcnt(0)" ::: "memory");                        \
    __builtin_amdgcn_sched_barrier(0);                                        \
    __builtin_amdgcn_s_barrier();          /* tile t fully in LDS */          \
    __builtin_amdgcn_sched_barrier(0);                                        \
    compute(CUR);                                                             \
    __builtin_amdgcn_sched_barrier(0);                                        \
    __builtin_amdgcn_s_barrier();          /* all reads of Bs/As[cur] done */ \
  }

  for (int t = 0; t < NT; t += 2) {
    GEMM12_STEP(t,     0, R1a, R3a);
    GEMM12_STEP(t + 1, 1, R1b, R3b);
  }
#undef GEMM12_STEP

  int rbase = m0 + wr * 32 + (lane >> 4) * 4;
  int cbase = n0 + wc * 32 + (lane & 15);
#pragma unroll
  for (int mi = 0; mi < 2; ++mi) {
#pragma unroll
    for (int ni = 0; ni < 2; ++ni) {
      int col = cbase + ni * 16;
#pragma unroll
      for (int r = 0; r < 4; ++r) {
        int row = rbase + mi * 16 + r;
        float v = acc1[mi][ni][r];
        if (EPI == 0) {
          float a3 = acc3[mi][ni][r];
          float sg = v / (1.f + __expf(-v));
          Cb[(long)row * ldcb + col] = f2bf(sg * a3);
        } else if (EPI == 1) {
          C0[(long)row * ldc0 + col] = v;
        } else {
          if (row < rowlim) {
            atomicAdd(&C0[(long)perm[row] * ldc0 + col], v * pwt[row]);
          }
        }
      }
    }
  }
}

extern "C" void kernel_launch(void* const* d_in, const int* in_sizes, int n_in,
                              void* d_out, int out_size, void* d_ws, size_t ws_size,
                              hipStream_t stream) {
  (void)in_sizes; (void)n_in; (void)out_size; (void)ws_size;
  const float* x   = (const float*)d_in[0];
  const float* gw  = (const float*)d_in[1];
  const float* w1  = (const float*)d_in[2];
  const float* w2  = (const float*)d_in[3];
  const float* w3  = (const float*)d_in[4];
  const float* sw1 = (const float*)d_in[5];
  const float* sw2 = (const float*)d_in[6];
  const float* sw3 = (const float*)d_in[7];
  float* out = (float*)d_out;
  char* ws = (char*)d_ws;

  int*   counts = (int*)(ws + 0);
  int*   cursor = (int*)(ws + 64);
  int*   off    = (int*)(ws + 128);
  int*   cap    = (int*)(ws + 192);
  float* ssum   = (float*)(ws + 256);
  int*   tile2e = (int*)(ws + 1024);
  int*   tile2m0= (int*)(ws + 2048);
  int*   idxb   = (int*)(ws + 4096);
  float* wtb    = (float*)(ws + 4096 + 32768);
  int*   perm   = (int*)(ws + 4096 + 65536);
  float* pwt    = (float*)(ws + 4096 + 65536 + 40960);
  u16*   xb     = (u16*)(ws + 262144);                 // 2048x2048 bf16
  double* logits = (double*)(ws + 8650752);            // 2048x16 f64
  u16*   hbuf   = (u16*)(ws + 16777216);               // 10240x1408 bf16
  u16*   hsb    = (u16*)(ws + 45613056);               // 2048x2816 bf16

  hipMemsetAsync(ws, 0, 512, stream);
  gatecvt_kernel<<<dim3(NTOK + 128), dim3(256), 0, stream>>>(x, gw, logits, xb);
  topk_kernel<<<dim3(NTOK / 256), dim3(256), 0, stream>>>(logits, idxb, wtb, counts, ssum);
  setup_kernel<<<dim3(1), dim3(256), 0, stream>>>(counts, off, cap, ssum, perm, pwt,
                                                  out + AUX_IDX, tile2e, tile2m0);
  scatter_kernel<<<dim3(8), dim3(256), 0, stream>>>(idxb, wtb, off, cursor, perm, pwt);

  // routed h = silu(gather(x)@w1^T) * (gather(x)@w3^T) -> bf16
  gemm12_kernel<true, true, 0><<<dim3(MAXTILES, HID / 64), dim3(512), 0, stream>>>(
      xb, DIM, w1, w3, DIM, (long)HID * DIM, DIM, tile2e, tile2m0,
      off, counts, perm, pwt, nullptr, 0, hbuf, HID, 0);
  // shared hs = silu(x@sw1^T) * (x@sw3^T) -> bf16
  gemm12_kernel<false, true, 0><<<dim3(NTOK / 128, SHID / 64), dim3(512), 0, stream>>>(
      xb, DIM, sw1, sw3, DIM, 0, DIM, nullptr, nullptr,
      nullptr, nullptr, nullptr, nullptr, nullptr, 0, hsb, SHID, NTOK);
  // z = hs @ sw2^T  (plain f32 store into out)
  gemm12_kernel<false, false, 1><<<dim3(NTOK / 128, DIM / 64), dim3(512), 0, stream>>>(
      hsb, SHID, sw2, nullptr, SHID, 0, SHID, nullptr, nullptr,
      nullptr, nullptr, nullptr, nullptr, out, DIM, nullptr, 0, NTOK);
  // out += (h @ w2^T) * pwt   (atomic accumulate on top of z)
  gemm12_kernel<false, false, 2><<<dim3(MAXTILES, DIM / 64), dim3(512), 0, stream>>>(
      hbuf, HID, w2, nullptr, HID, (long)DIM * HID, HID, tile2e, tile2m0,
      off, counts, perm, pwt, out, DIM, nullptr, 0, 0);
}